// Round 1
// baseline (357.395 us; speedup 1.0000x reference)
//
#include <hip/hip_runtime.h>

// ---------------------------------------------------------------------------
// network_49581102465567: 5-layer linear MLP, codebook quantize after layer 2.
// Linear layers fold: Wa = w2@w1 [512x1024], Wc = (w5@w4)@w3 [512x512].
// Round 6: main-GEMM restructure + dispatch merge.
//  - gemm_main: 128x128 tile, BK=64, padded LDS (stride 72 bf16 = 144B = 36
//    banks == 4 mod 32 -> 2-way reads, free), register prefetch of next
//    k-tile under the MFMA phase, grid.y 8->4 (halves fp32 x re-reads).
//  - fold GEMMs: padded LDS stride 40 (80B = 20 banks -> 2-way).
//  - dispatch merge 12 -> 7: {3 transposes}, {fold1+fold2}, {red1+red2},
//    {fold3+bias}. part2 aliases q (both 16MB, lifetimes disjoint).
// Numerics bit-identical to R5: same RNE casts, same K-accum order, same
// split-K reduce order, same quantize search.
// ---------------------------------------------------------------------------

typedef __bf16 v8bf __attribute__((ext_vector_type(8)));
typedef float  v4f  __attribute__((ext_vector_type(4)));

#define Bdim   16384
#define DIN    1024
#define DOUT   512
#define H1dim  4096
#define H3dim  2048
#define H4dim  2048

__device__ __forceinline__ unsigned pack2bf(float a, float b) {
  return (unsigned)__builtin_bit_cast(unsigned short, (__bf16)a) |
         ((unsigned)__builtin_bit_cast(unsigned short, (__bf16)b) << 16);
}

// ---- transpose + cast: in fp32 [R][C] -> out bf16 [C][R], 3 merged ----
__device__ __forceinline__ void transpose_body(const float* __restrict__ in,
                                               __bf16* __restrict__ out,
                                               int R, int C, int bx, int by,
                                               float (*tile)[33]) {
  const int c0 = bx * 32, r0 = by * 32;
  const int t = threadIdx.x, tr = t >> 5, tc = t & 31;
#pragma unroll
  for (int i = 0; i < 4; ++i)
    tile[tr + i * 8][tc] = in[(size_t)(r0 + tr + i * 8) * C + (c0 + tc)];
  __syncthreads();
#pragma unroll
  for (int i = 0; i < 4; ++i)
    out[(size_t)(c0 + tr + i * 8) * R + (r0 + tc)] = (__bf16)tile[tc][tr + i * 8];
}

__global__ void transpose3_kernel(const float* __restrict__ w1, __bf16* __restrict__ w1T,
                                  const float* __restrict__ w4, __bf16* __restrict__ w4T,
                                  const float* __restrict__ w3, __bf16* __restrict__ w3T) {
  __shared__ float tile[32][33];
  int b = blockIdx.x;
  if (b < 4096) {
    transpose_body(w1, w1T, H1dim, DIN, b & 31, b >> 5, tile);          // grid (32,128)
  } else if (b < 8192) {
    b -= 4096;
    transpose_body(w4, w4T, H4dim, H3dim, b & 63, b >> 6, tile);        // grid (64,64)
  } else {
    b -= 8192;
    transpose_body(w3, w3T, H3dim, DOUT, b & 15, b >> 4, tile);         // grid (16,64)
  }
}

// ---- folded bias vectors (identical math to R5) ----
__device__ __forceinline__ void bias_body(int bb, const float* __restrict__ b1,
                                          const float* __restrict__ w2,
                                          const float* __restrict__ b2,
                                          const float* __restrict__ b3,
                                          const __bf16* __restrict__ WtT,
                                          const float* __restrict__ b4,
                                          const float* __restrict__ w5,
                                          const float* __restrict__ b5,
                                          float* __restrict__ ba, float* __restrict__ bc) {
  const int wave = threadIdx.x >> 6, lane = threadIdx.x & 63;
  if (bb < 128) {
    const int j = bb * 4 + wave;
    float s = 0.f;
    for (int k = lane; k < H1dim; k += 64) s += b1[k] * w2[(size_t)j * H1dim + k];
#pragma unroll
    for (int off = 32; off; off >>= 1) s += __shfl_xor(s, off, 64);
    if (lane == 0) ba[j] = s + b2[j];
  } else {
    const int j = (bb - 128) * 4 + wave;
    float s = 0.f;
    for (int k = lane; k < H4dim; k += 64)
      s += b3[k] * (float)WtT[(size_t)j * H4dim + k] + b4[k] * w5[(size_t)j * H4dim + k];
#pragma unroll
    for (int off = 32; off; off >>= 1) s += __shfl_xor(s, off, 64);
    if (lane == 0) bc[j] = s + b5[j];
  }
}

// ---- split-K fold GEMM body: 64x64 tile, BK=32, padded LDS stride 40 ----
template <bool ABF16>
__device__ __forceinline__ void splitk_body(__bf16* As, __bf16* Bs,
                                            int bx, int by, int bz,
                                            const void* __restrict__ Ain,
                                            const __bf16* __restrict__ Bt,
                                            float* __restrict__ Cpart,
                                            int M, int N, int K, int Kchunk) {
  const int t = threadIdx.x;
  const int m0 = bx * 64, n0 = by * 64;
  const int kbeg = bz * Kchunk;
  const int lane = t & 63, wave = t >> 6;
  const int quad = lane >> 4, l15 = lane & 15;
  const int wm = (wave & 1) * 32, wn = (wave >> 1) * 32;

  v4f acc[2][2];
#pragma unroll
  for (int i = 0; i < 2; ++i)
#pragma unroll
    for (int j = 0; j < 2; ++j) acc[i][j] = (v4f){0.f, 0.f, 0.f, 0.f};

  const int r = t >> 2, c = (t & 3) * 8;   // 16B chunk coords over 64x32
  for (int k0 = kbeg; k0 < kbeg + Kchunk; k0 += 32) {
    if constexpr (ABF16) {
      const __bf16* A = (const __bf16*)Ain;
      *(int4*)&As[r * 40 + c] = *(const int4*)&A[(size_t)(m0 + r) * K + (k0 + c)];
    } else {
      const float* A = (const float*)Ain;
#pragma unroll
      for (int p = 0; p < 2; ++p) {
        const int idx = p * 256 + t;
        const int row = idx >> 3, col = (idx & 7) * 4;
        float4 v = *(const float4*)&A[(size_t)(m0 + row) * K + (k0 + col)];
        uint2 o;
        o.x = pack2bf(v.x, v.y);
        o.y = pack2bf(v.z, v.w);
        *(uint2*)&As[row * 40 + col] = o;
      }
    }
    *(int4*)&Bs[r * 40 + c] = *(const int4*)&Bt[(size_t)(n0 + r) * K + (k0 + c)];
    __syncthreads();
    v8bf af[2], bfr[2];
#pragma unroll
    for (int i = 0; i < 2; ++i) {
      af[i]  = *(const v8bf*)&As[(wm + i * 16 + l15) * 40 + quad * 8];
      bfr[i] = *(const v8bf*)&Bs[(wn + i * 16 + l15) * 40 + quad * 8];
    }
#pragma unroll
    for (int i = 0; i < 2; ++i)
#pragma unroll
      for (int j = 0; j < 2; ++j)
        acc[i][j] = __builtin_amdgcn_mfma_f32_16x16x32_bf16(af[i], bfr[j], acc[i][j], 0, 0, 0);
    __syncthreads();
  }

  float* dst = Cpart + (size_t)bz * M * N;
#pragma unroll
  for (int i = 0; i < 2; ++i)
#pragma unroll
    for (int j = 0; j < 2; ++j)
#pragma unroll
      for (int r2 = 0; r2 < 4; ++r2) {
        const int gm = m0 + wm + i * 16 + quad * 4 + r2;
        const int gn = n0 + wn + j * 16 + l15;
        dst[(size_t)gm * N + gn] = acc[i][j][r2];
      }
}

// fold1 (w2@w1, 1024 blocks) + fold2 (w5@w4, 1024 blocks) in one dispatch
__global__ __launch_bounds__(256, 4)
void fold12_kernel(const float* __restrict__ w2, const __bf16* __restrict__ w1T,
                   float* __restrict__ part1,
                   const float* __restrict__ w5, const __bf16* __restrict__ w4T,
                   float* __restrict__ part2) {
  __shared__ __align__(16) __bf16 As[64 * 40];
  __shared__ __align__(16) __bf16 Bs[64 * 40];
  int b = blockIdx.x;
  if (b < 1024) {
    splitk_body<false>(As, Bs, b & 7, (b >> 3) & 15, b >> 7,
                       w2, w1T, part1, DOUT, DIN, H1dim, H1dim / 8);
  } else {
    b -= 1024;
    splitk_body<false>(As, Bs, b & 7, (b >> 3) & 31, b >> 8,
                       w5, w4T, part2, DOUT, H3dim, H4dim, H4dim / 4);
  }
}

// fold3 (WtT@w3, 512 blocks) + folded biases (256 blocks) in one dispatch
__global__ __launch_bounds__(256, 4)
void fold3_bias_kernel(const __bf16* __restrict__ WtT, const __bf16* __restrict__ w3T,
                       float* __restrict__ part,
                       const float* __restrict__ b1, const float* __restrict__ w2,
                       const float* __restrict__ b2, const float* __restrict__ b3,
                       const float* __restrict__ b4, const float* __restrict__ w5,
                       const float* __restrict__ b5,
                       float* __restrict__ ba, float* __restrict__ bc) {
  __shared__ __align__(16) __bf16 As[64 * 40];
  __shared__ __align__(16) __bf16 Bs[64 * 40];
  int b = blockIdx.x;
  if (b < 512) {
    splitk_body<true>(As, Bs, b & 7, (b >> 3) & 7, b >> 6,
                      WtT, w3T, part, DOUT, DOUT, H3dim, H3dim / 8);
  } else {
    bias_body(b - 512, b1, w2, b2, b3, WtT, b4, w5, b5, ba, bc);
  }
}

// ---- reduce S fp32 partial slices -> bf16; red1 + red2 merged ----
__device__ __forceinline__ void reduce_body(const float* __restrict__ part,
                                            __bf16* __restrict__ out, int MN4, int S, int i) {
  if (i >= MN4) return;
  const float4* p = reinterpret_cast<const float4*>(part);
  float4 s = p[i];
  for (int k = 1; k < S; ++k) {
    float4 v = p[(size_t)k * MN4 + i];
    s.x += v.x; s.y += v.y; s.z += v.z; s.w += v.w;
  }
  uint2 o;
  o.x = pack2bf(s.x, s.y);
  o.y = pack2bf(s.z, s.w);
  reinterpret_cast<uint2*>(out)[i] = o;
}

__global__ void reduce12_kernel(const float* __restrict__ part1, __bf16* __restrict__ WaT,
                                const float* __restrict__ part2, __bf16* __restrict__ WtT) {
  const int b = blockIdx.x, t = threadIdx.x;
  if (b < 512) reduce_body(part1, WaT, DOUT * DIN / 4, 8, b * 256 + t);
  else         reduce_body(part2, WtT, DOUT * H3dim / 4, 4, (b - 512) * 256 + t);
}

__global__ void reduce_cast_kernel(const float* __restrict__ part,
                                   __bf16* __restrict__ out, int MN4, int S) {
  int i = blockIdx.x * blockDim.x + threadIdx.x;
  reduce_body(part, out, MN4, S, i);
}

// ---- main B^T-form GEMM: 128x128 tile, BK=64, 4 waves 2x2 (64x64 each) ----
// Padded LDS stride 72 bf16 (144B = 36 banks == 4 mod 32 -> 2-way reads).
// Register prefetch: next k-tile global loads issue before the MFMA phase.
enum { MODE_Q = 1, MODE_OUT = 2 };

template <int MODE>
__global__ __launch_bounds__(256)
void gemm_main_kernel(const void* __restrict__ Ain, const __bf16* __restrict__ Bt,
                      void* __restrict__ Cout, const float* __restrict__ bias,
                      const float* __restrict__ codebook, int M, int N, int K) {
  __shared__ __align__(16) __bf16 As[128 * 72];   // 18 KB
  __shared__ __align__(16) __bf16 Bs[128 * 72];   // 18 KB
  __shared__ float cbs[256];

  const int t = threadIdx.x;
  const int m0 = blockIdx.x * 128;
  const int n0 = blockIdx.y * 128;
  if constexpr (MODE == MODE_Q) cbs[t] = codebook[t];

  const int lane = t & 63, wave = t >> 6;
  const int quad = lane >> 4, l15 = lane & 15;
  const int wm = (wave & 1) * 64, wn = (wave >> 1) * 64;

  const float*  Af = (const float*)Ain;
  const __bf16* Ab = (const __bf16*)Ain;

  // staging coords
  const int frow = t >> 4, fcol = (t & 15) * 4;   // fp32 path: 16 thr/row (64 floats)
  const int hrow = t >> 3, hcol = (t & 7) * 8;    // bf16 path: 8 thr/row (64 bf16)

  float4 pa[8];   // MODE_Q  A prefetch (128x64 fp32 -> 8 float4/thread)
  int4   pab[4];  // MODE_OUT A prefetch (128x64 bf16 -> 4 int4/thread)
  int4   pb[4];   // B prefetch (128x64 bf16)

  auto prefetch = [&](int k0) {
    if constexpr (MODE == MODE_Q) {
#pragma unroll
      for (int p = 0; p < 8; ++p)
        pa[p] = *(const float4*)&Af[(size_t)(m0 + p * 16 + frow) * K + (k0 + fcol)];
    } else {
#pragma unroll
      for (int p = 0; p < 4; ++p)
        pab[p] = *(const int4*)&Ab[(size_t)(m0 + p * 32 + hrow) * K + (k0 + hcol)];
    }
#pragma unroll
    for (int p = 0; p < 4; ++p)
      pb[p] = *(const int4*)&Bt[(size_t)(n0 + p * 32 + hrow) * K + (k0 + hcol)];
  };
  auto writelds = [&]() {
    if constexpr (MODE == MODE_Q) {
#pragma unroll
      for (int p = 0; p < 8; ++p) {
        uint2 o;
        o.x = pack2bf(pa[p].x, pa[p].y);
        o.y = pack2bf(pa[p].z, pa[p].w);
        *(uint2*)&As[(p * 16 + frow) * 72 + fcol] = o;
      }
    } else {
#pragma unroll
      for (int p = 0; p < 4; ++p)
        *(int4*)&As[(p * 32 + hrow) * 72 + hcol] = pab[p];
    }
#pragma unroll
    for (int p = 0; p < 4; ++p)
      *(int4*)&Bs[(p * 32 + hrow) * 72 + hcol] = pb[p];
  };

  v4f acc[4][4];
#pragma unroll
  for (int i = 0; i < 4; ++i)
#pragma unroll
    for (int j = 0; j < 4; ++j) acc[i][j] = (v4f){0.f, 0.f, 0.f, 0.f};

  prefetch(0);
  for (int k0 = 0; k0 < K; k0 += 64) {
    writelds();
    __syncthreads();
    if (k0 + 64 < K) prefetch(k0 + 64);   // hide next-tile latency under MFMA
#pragma unroll
    for (int kk = 0; kk < 2; ++kk) {      // kk ascending: same K order as BK=32
      v8bf af[4], bv[4];
#pragma unroll
      for (int i = 0; i < 4; ++i)
        af[i] = *(const v8bf*)&As[(wm + i * 16 + l15) * 72 + kk * 32 + quad * 8];
#pragma unroll
      for (int j = 0; j < 4; ++j)
        bv[j] = *(const v8bf*)&Bs[(wn + j * 16 + l15) * 72 + kk * 32 + quad * 8];
#pragma unroll
      for (int i = 0; i < 4; ++i)
#pragma unroll
        for (int j = 0; j < 4; ++j)
          acc[i][j] = __builtin_amdgcn_mfma_f32_16x16x32_bf16(af[i], bv[j], acc[i][j], 0, 0, 0);
    }
    __syncthreads();
  }

#pragma unroll
  for (int i = 0; i < 4; ++i) {
#pragma unroll
    for (int j = 0; j < 4; ++j) {
#pragma unroll
      for (int r = 0; r < 4; ++r) {
        const int gm = m0 + wm + i * 16 + quad * 4 + r;
        const int gn = n0 + wn + j * 16 + l15;
        float v = acc[i][j][r] + bias[gn];
        if constexpr (MODE == MODE_Q) {
          int idx = 0;
#pragma unroll
          for (int s = 128; s > 0; s >>= 1) {
            const int u = idx + s;
            if (cbs[u] <= v) idx = u;
          }
          float best = cbs[idx];
          if (idx < 255) {
            const float c1 = cbs[idx + 1];
            if (!(v - best <= c1 - v)) best = c1;
          }
          ((__bf16*)Cout)[(size_t)gm * N + gn] = (__bf16)best;
        } else {
          ((float*)Cout)[(size_t)gm * N + gn] = v;
        }
      }
    }
  }
}

extern "C" void kernel_launch(void* const* d_in, const int* in_sizes, int n_in,
                              void* d_out, int out_size, void* d_ws, size_t ws_size,
                              hipStream_t stream) {
  const float* x  = (const float*)d_in[0];
  const float* cb = (const float*)d_in[1];
  const float* w1 = (const float*)d_in[2];   // [4096,1024]
  const float* b1 = (const float*)d_in[3];
  const float* w2 = (const float*)d_in[4];   // [512,4096]
  const float* b2 = (const float*)d_in[5];
  const float* w3 = (const float*)d_in[6];   // [2048,512]
  const float* b3 = (const float*)d_in[7];
  const float* w4 = (const float*)d_in[8];   // [2048,2048]
  const float* b4 = (const float*)d_in[9];
  const float* w5 = (const float*)d_in[10];  // [512,2048]
  const float* b5 = (const float*)d_in[11];
  float* out = (float*)d_out;

  char* ws = (char*)d_ws;
  size_t off = 0;
  auto alloc = [&](size_t bytes) -> void* {
    void* p = ws + off;
    off = (off + bytes + 255) & ~(size_t)255;
    return p;
  };
  __bf16* w1T  = (__bf16*)alloc((size_t)DIN * H1dim * 2);
  __bf16* w4T  = (__bf16*)alloc((size_t)H3dim * H4dim * 2);
  __bf16* w3T  = (__bf16*)alloc((size_t)DOUT * H3dim * 2);
  __bf16* WaT  = (__bf16*)alloc((size_t)DOUT * DIN * 2);
  __bf16* WtT  = (__bf16*)alloc((size_t)DOUT * H3dim * 2);
  __bf16* WcT  = (__bf16*)alloc((size_t)DOUT * DOUT * 2);
  __bf16* q    = (__bf16*)alloc((size_t)Bdim * DOUT * 2);      // 16 MB
  float*  ba   = (float*)alloc(DOUT * 4);
  float*  bc   = (float*)alloc(DOUT * 4);
  float*  part1 = (float*)alloc((size_t)8 * DOUT * DIN * 4);   // 16 MB
  // part2 (4*512*2048*4 = 16 MB) aliases q (16384*512*2 = 16 MB):
  // fold12 writes part2, reduce12 consumes it, q is written only afterwards.
  float*  part2 = (float*)q;

  // 1) all three weight transposes in one dispatch
  transpose3_kernel<<<9216, 256, 0, stream>>>(w1, w1T, w4, w4T, w3, w3T);

  // 2) fold1 (WaT partials) + fold2 (WtT partials) in one dispatch
  fold12_kernel<<<2048, 256, 0, stream>>>(w2, w1T, part1, w5, w4T, part2);

  // 3) both reductions in one dispatch
  reduce12_kernel<<<1536, 256, 0, stream>>>(part1, WaT, part2, WtT);

  // 4) fold3 (WcT partials, reuses part1) + folded biases (needs WtT)
  fold3_bias_kernel<<<768, 256, 0, stream>>>(WtT, w3T, part1,
                                             b1, w2, b2, b3, b4, w5, b5, ba, bc);

  // 5) reduce fold3 -> WcT
  reduce_cast_kernel<<<256, 256, 0, stream>>>(part1, WcT, DOUT * DOUT / 4, 8);

  // 6) h2 = x@Wa + ba -> quantize -> q (A fp32, cast in staging)
  gemm_main_kernel<MODE_Q><<<dim3(Bdim / 128, DOUT / 128), 256, 0, stream>>>(
      x, WaT, q, ba, cb, Bdim, DOUT, DIN);

  // 7) out = q@Wc + bc (A bf16)
  gemm_main_kernel<MODE_OUT><<<dim3(Bdim / 128, DOUT / 128), 256, 0, stream>>>(
      q, WcT, out, bc, nullptr, Bdim, DOUT, DOUT);
}

// Round 2
// 304.105 us; speedup vs baseline: 1.1752x; 1.1752x over previous
//
#include <hip/hip_runtime.h>

// ---------------------------------------------------------------------------
// network_49581102465567: 5-layer linear MLP, codebook quantize after layer 2.
// Linear layers fold: Wa = w2@w1 [512x1024], Wc = (w5@w4)@w3 [512x512].
// Round 7: revert main GEMM to R5 skeleton (128x64 tile, 1024 blocks, DMA
// staging), then fix its three measured costs:
//  - x pre-cast to bf16 (fused into transpose dispatch) -> all-bf16 main
//    GEMMs, DMA both operands, no fp32 VALU cast in hot loop.
//  - BK=64 (half the barriers) + XOR chunk swizzle via pre-swizzled GLOBAL
//    source (LDS dest stays linear as global_load_lds requires); reads use
//    the same XOR -> 8-way bank conflicts become 2-way (free).
//  - grid (128,8)=1024 blocks = 4 blocks/CU, LDS 25 KB, ~50% occupancy.
// Numerics bit-identical: same RNE casts, same ascending-K accumulate order,
// fold/reduce/bias paths unchanged from R6 (which verified).
// ---------------------------------------------------------------------------

typedef __bf16 v8bf __attribute__((ext_vector_type(8)));
typedef float  v4f  __attribute__((ext_vector_type(4)));

#define Bdim   16384
#define DIN    1024
#define DOUT   512
#define H1dim  4096
#define H3dim  2048
#define H4dim  2048

#define GLOBAL_AS __attribute__((address_space(1)))
#define LDS_AS    __attribute__((address_space(3)))

__device__ __forceinline__ void load16_to_lds(const __bf16* g, __bf16* l) {
  __builtin_amdgcn_global_load_lds((const GLOBAL_AS unsigned int*)g,
                                   (LDS_AS unsigned int*)l, 16, 0, 0);
}

__device__ __forceinline__ unsigned pack2bf(float a, float b) {
  return (unsigned)__builtin_bit_cast(unsigned short, (__bf16)a) |
         ((unsigned)__builtin_bit_cast(unsigned short, (__bf16)b) << 16);
}

// ---- transpose + cast bodies; 3 transposes + x-cast in ONE dispatch ----
__device__ __forceinline__ void transpose_body(const float* __restrict__ in,
                                               __bf16* __restrict__ out,
                                               int R, int C, int bx, int by,
                                               float (*tile)[33]) {
  const int c0 = bx * 32, r0 = by * 32;
  const int t = threadIdx.x, tr = t >> 5, tc = t & 31;
#pragma unroll
  for (int i = 0; i < 4; ++i)
    tile[tr + i * 8][tc] = in[(size_t)(r0 + tr + i * 8) * C + (c0 + tc)];
  __syncthreads();
#pragma unroll
  for (int i = 0; i < 4; ++i)
    out[(size_t)(c0 + tr + i * 8) * R + (r0 + tc)] = (__bf16)tile[tc][tr + i * 8];
}

__global__ void prep_kernel(const float* __restrict__ w1, __bf16* __restrict__ w1T,
                            const float* __restrict__ w4, __bf16* __restrict__ w4T,
                            const float* __restrict__ w3, __bf16* __restrict__ w3T,
                            const float* __restrict__ x, __bf16* __restrict__ xb) {
  __shared__ float tile[32][33];
  int b = blockIdx.x;
  if (b < 4096) {
    transpose_body(w1, w1T, H1dim, DIN, b & 31, b >> 5, tile);          // grid (32,128)
  } else if (b < 8192) {
    b -= 4096;
    transpose_body(w4, w4T, H4dim, H3dim, b & 63, b >> 6, tile);        // grid (64,64)
  } else if (b < 9216) {
    b -= 8192;
    transpose_body(w3, w3T, H3dim, DOUT, b & 15, b >> 4, tile);         // grid (16,64)
  } else {
    // x fp32 -> bf16, 8 elems/thread (RNE, same values as in-staging cast)
    const size_t i = (size_t)(b - 9216) * 2048 + (size_t)threadIdx.x * 8;
    float4 a = *(const float4*)&x[i];
    float4 c = *(const float4*)&x[i + 4];
    int4 o;
    o.x = pack2bf(a.x, a.y); o.y = pack2bf(a.z, a.w);
    o.z = pack2bf(c.x, c.y); o.w = pack2bf(c.z, c.w);
    *(int4*)&xb[i] = o;
  }
}

// ---- folded bias vectors (identical math to R5/R6) ----
__device__ __forceinline__ void bias_body(int bb, const float* __restrict__ b1,
                                          const float* __restrict__ w2,
                                          const float* __restrict__ b2,
                                          const float* __restrict__ b3,
                                          const __bf16* __restrict__ WtT,
                                          const float* __restrict__ b4,
                                          const float* __restrict__ w5,
                                          const float* __restrict__ b5,
                                          float* __restrict__ ba, float* __restrict__ bc) {
  const int wave = threadIdx.x >> 6, lane = threadIdx.x & 63;
  if (bb < 128) {
    const int j = bb * 4 + wave;
    float s = 0.f;
    for (int k = lane; k < H1dim; k += 64) s += b1[k] * w2[(size_t)j * H1dim + k];
#pragma unroll
    for (int off = 32; off; off >>= 1) s += __shfl_xor(s, off, 64);
    if (lane == 0) ba[j] = s + b2[j];
  } else {
    const int j = (bb - 128) * 4 + wave;
    float s = 0.f;
    for (int k = lane; k < H4dim; k += 64)
      s += b3[k] * (float)WtT[(size_t)j * H4dim + k] + b4[k] * w5[(size_t)j * H4dim + k];
#pragma unroll
    for (int off = 32; off; off >>= 1) s += __shfl_xor(s, off, 64);
    if (lane == 0) bc[j] = s + b5[j];
  }
}

// ---- split-K fold GEMM body: 64x64 tile, BK=32, padded LDS stride 40 ----
template <bool ABF16>
__device__ __forceinline__ void splitk_body(__bf16* As, __bf16* Bs,
                                            int bx, int by, int bz,
                                            const void* __restrict__ Ain,
                                            const __bf16* __restrict__ Bt,
                                            float* __restrict__ Cpart,
                                            int M, int N, int K, int Kchunk) {
  const int t = threadIdx.x;
  const int m0 = bx * 64, n0 = by * 64;
  const int kbeg = bz * Kchunk;
  const int lane = t & 63, wave = t >> 6;
  const int quad = lane >> 4, l15 = lane & 15;
  const int wm = (wave & 1) * 32, wn = (wave >> 1) * 32;

  v4f acc[2][2];
#pragma unroll
  for (int i = 0; i < 2; ++i)
#pragma unroll
    for (int j = 0; j < 2; ++j) acc[i][j] = (v4f){0.f, 0.f, 0.f, 0.f};

  const int r = t >> 2, c = (t & 3) * 8;   // 16B chunk coords over 64x32
  for (int k0 = kbeg; k0 < kbeg + Kchunk; k0 += 32) {
    if constexpr (ABF16) {
      const __bf16* A = (const __bf16*)Ain;
      *(int4*)&As[r * 40 + c] = *(const int4*)&A[(size_t)(m0 + r) * K + (k0 + c)];
    } else {
      const float* A = (const float*)Ain;
#pragma unroll
      for (int p = 0; p < 2; ++p) {
        const int idx = p * 256 + t;
        const int row = idx >> 3, col = (idx & 7) * 4;
        float4 v = *(const float4*)&A[(size_t)(m0 + row) * K + (k0 + col)];
        uint2 o;
        o.x = pack2bf(v.x, v.y);
        o.y = pack2bf(v.z, v.w);
        *(uint2*)&As[row * 40 + col] = o;
      }
    }
    *(int4*)&Bs[r * 40 + c] = *(const int4*)&Bt[(size_t)(n0 + r) * K + (k0 + c)];
    __syncthreads();
    v8bf af[2], bfr[2];
#pragma unroll
    for (int i = 0; i < 2; ++i) {
      af[i]  = *(const v8bf*)&As[(wm + i * 16 + l15) * 40 + quad * 8];
      bfr[i] = *(const v8bf*)&Bs[(wn + i * 16 + l15) * 40 + quad * 8];
    }
#pragma unroll
    for (int i = 0; i < 2; ++i)
#pragma unroll
      for (int j = 0; j < 2; ++j)
        acc[i][j] = __builtin_amdgcn_mfma_f32_16x16x32_bf16(af[i], bfr[j], acc[i][j], 0, 0, 0);
    __syncthreads();
  }

  float* dst = Cpart + (size_t)bz * M * N;
#pragma unroll
  for (int i = 0; i < 2; ++i)
#pragma unroll
    for (int j = 0; j < 2; ++j)
#pragma unroll
      for (int r2 = 0; r2 < 4; ++r2) {
        const int gm = m0 + wm + i * 16 + quad * 4 + r2;
        const int gn = n0 + wn + j * 16 + l15;
        dst[(size_t)gm * N + gn] = acc[i][j][r2];
      }
}

// fold1 (w2@w1, 1024 blocks) + fold2 (w5@w4, 1024 blocks) in one dispatch
__global__ __launch_bounds__(256, 4)
void fold12_kernel(const float* __restrict__ w2, const __bf16* __restrict__ w1T,
                   float* __restrict__ part1,
                   const float* __restrict__ w5, const __bf16* __restrict__ w4T,
                   float* __restrict__ part2) {
  __shared__ __align__(16) __bf16 As[64 * 40];
  __shared__ __align__(16) __bf16 Bs[64 * 40];
  int b = blockIdx.x;
  if (b < 1024) {
    splitk_body<false>(As, Bs, b & 7, (b >> 3) & 15, b >> 7,
                       w2, w1T, part1, DOUT, DIN, H1dim, H1dim / 8);
  } else {
    b -= 1024;
    splitk_body<false>(As, Bs, b & 7, (b >> 3) & 31, b >> 8,
                       w5, w4T, part2, DOUT, H3dim, H4dim, H4dim / 4);
  }
}

// fold3 (WtT@w3, 512 blocks) + folded biases (256 blocks) in one dispatch
__global__ __launch_bounds__(256, 4)
void fold3_bias_kernel(const __bf16* __restrict__ WtT, const __bf16* __restrict__ w3T,
                       float* __restrict__ part,
                       const float* __restrict__ b1, const float* __restrict__ w2,
                       const float* __restrict__ b2, const float* __restrict__ b3,
                       const float* __restrict__ b4, const float* __restrict__ w5,
                       const float* __restrict__ b5,
                       float* __restrict__ ba, float* __restrict__ bc) {
  __shared__ __align__(16) __bf16 As[64 * 40];
  __shared__ __align__(16) __bf16 Bs[64 * 40];
  int b = blockIdx.x;
  if (b < 512) {
    splitk_body<true>(As, Bs, b & 7, (b >> 3) & 7, b >> 6,
                      WtT, w3T, part, DOUT, DOUT, H3dim, H3dim / 8);
  } else {
    bias_body(b - 512, b1, w2, b2, b3, WtT, b4, w5, b5, ba, bc);
  }
}

// ---- reduce S fp32 partial slices -> bf16; red1 + red2 merged ----
__device__ __forceinline__ void reduce_body(const float* __restrict__ part,
                                            __bf16* __restrict__ out, int MN4, int S, int i) {
  if (i >= MN4) return;
  const float4* p = reinterpret_cast<const float4*>(part);
  float4 s = p[i];
  for (int k = 1; k < S; ++k) {
    float4 v = p[(size_t)k * MN4 + i];
    s.x += v.x; s.y += v.y; s.z += v.z; s.w += v.w;
  }
  uint2 o;
  o.x = pack2bf(s.x, s.y);
  o.y = pack2bf(s.z, s.w);
  reinterpret_cast<uint2*>(out)[i] = o;
}

__global__ void reduce12_kernel(const float* __restrict__ part1, __bf16* __restrict__ WaT,
                                const float* __restrict__ part2, __bf16* __restrict__ WtT) {
  const int b = blockIdx.x, t = threadIdx.x;
  if (b < 512) reduce_body(part1, WaT, DOUT * DIN / 4, 8, b * 256 + t);
  else         reduce_body(part2, WtT, DOUT * H3dim / 4, 4, (b - 512) * 256 + t);
}

__global__ void reduce_cast_kernel(const float* __restrict__ part,
                                   __bf16* __restrict__ out, int MN4, int S) {
  int i = blockIdx.x * blockDim.x + threadIdx.x;
  reduce_body(part, out, MN4, S, i);
}

// ---- main GEMM: 128x64 tile, BK=64, all-bf16, DMA staging, XOR swizzle ----
// LDS linear [rows][64] bf16 (row = 128 B = 32 banks, stride == 0 mod 32).
// global_load_lds writes linearly (dest = base + lane*16); the SOURCE address
// is pre-swizzled per lane: chunk_g = chunk_lin ^ (row & 7). Fragment reads
// apply the same XOR -> 16-lane groups hit 8 chunk slots x2 = 2-way (free).
// K order: kk=0,1 ascending within BK=64 == same accumulate order as BK=32.
enum { MODE_Q = 1, MODE_OUT = 2 };

template <int MODE>
__global__ __launch_bounds__(256, 4)
void gemm_main_kernel(const __bf16* __restrict__ A, const __bf16* __restrict__ Bt,
                      void* __restrict__ Cout, const float* __restrict__ bias,
                      const float* __restrict__ codebook, int M, int N, int K) {
  __shared__ __align__(16) __bf16 As[128 * 64];   // 16 KB
  __shared__ __align__(16) __bf16 Bs[64 * 64];    // 8 KB
  __shared__ float cbs[256];

  const int t = threadIdx.x;
  const int m0 = blockIdx.x * 128;
  const int n0 = blockIdx.y * 64;
  if constexpr (MODE == MODE_Q) cbs[t] = codebook[t];

  const int lane = t & 63, wave = t >> 6;
  const int quad = lane >> 4, l15 = lane & 15;
  const int wm = (wave & 1) * 64, wn = (wave >> 1) * 32;

  // staging: each gload covers 8 rows (64 lanes x 16B = 8 x 128B rows).
  // lane -> (row = base + lane>>3, lin chunk = lane&7); source chunk XOR'd.
  const int lrow = lane >> 3;
  const int gcol = (((lane & 7) ^ lrow) * 8);     // bf16 elems, swizzled source

  const __bf16* gA = A  + (size_t)(m0 + 32 * wave + lrow) * K + gcol;
  const __bf16* gB = Bt + (size_t)(n0 + 16 * wave + lrow) * K + gcol;
  __bf16* lA = &As[32 * wave * 64];
  __bf16* lB = &Bs[16 * wave * 64];

  v4f acc[4][2];
#pragma unroll
  for (int i = 0; i < 4; ++i)
#pragma unroll
    for (int j = 0; j < 2; ++j) acc[i][j] = (v4f){0.f, 0.f, 0.f, 0.f};

  const int swz = l15 & 7;                        // read-side XOR (row & 7)

  for (int k0 = 0; k0 < K; k0 += 64) {
#pragma unroll
    for (int p = 0; p < 4; ++p)
      load16_to_lds(gA + (size_t)(8 * p) * K + k0, lA + p * 512);
#pragma unroll
    for (int p = 0; p < 2; ++p)
      load16_to_lds(gB + (size_t)(8 * p) * K + k0, lB + p * 512);
    __syncthreads();

#pragma unroll
    for (int kk = 0; kk < 2; ++kk) {
      const int cch = ((kk * 4 + quad) ^ swz) * 8;
      v8bf af[4], bv[2];
#pragma unroll
      for (int i = 0; i < 4; ++i)
        af[i] = *(const v8bf*)&As[(wm + i * 16 + l15) * 64 + cch];
#pragma unroll
      for (int j = 0; j < 2; ++j)
        bv[j] = *(const v8bf*)&Bs[(wn + j * 16 + l15) * 64 + cch];
#pragma unroll
      for (int i = 0; i < 4; ++i)
#pragma unroll
        for (int j = 0; j < 2; ++j)
          acc[i][j] = __builtin_amdgcn_mfma_f32_16x16x32_bf16(af[i], bv[j], acc[i][j], 0, 0, 0);
    }
    __syncthreads();
  }

#pragma unroll
  for (int j = 0; j < 2; ++j) {
    const int gn = n0 + wn + j * 16 + l15;
    const float bj = bias[gn];
#pragma unroll
    for (int i = 0; i < 4; ++i) {
#pragma unroll
      for (int r = 0; r < 4; ++r) {
        const int gm = m0 + wm + i * 16 + quad * 4 + r;
        float v = acc[i][j][r] + bj;
        if constexpr (MODE == MODE_Q) {
          int idx = 0;
#pragma unroll
          for (int s = 128; s > 0; s >>= 1) {
            const int u = idx + s;
            if (cbs[u] <= v) idx = u;
          }
          float best = cbs[idx];
          if (idx < 255) {
            const float c1 = cbs[idx + 1];
            if (!(v - best <= c1 - v)) best = c1;
          }
          ((__bf16*)Cout)[(size_t)gm * N + gn] = (__bf16)best;
        } else {
          ((float*)Cout)[(size_t)gm * N + gn] = v;
        }
      }
    }
  }
}

extern "C" void kernel_launch(void* const* d_in, const int* in_sizes, int n_in,
                              void* d_out, int out_size, void* d_ws, size_t ws_size,
                              hipStream_t stream) {
  const float* x  = (const float*)d_in[0];
  const float* cb = (const float*)d_in[1];
  const float* w1 = (const float*)d_in[2];   // [4096,1024]
  const float* b1 = (const float*)d_in[3];
  const float* w2 = (const float*)d_in[4];   // [512,4096]
  const float* b2 = (const float*)d_in[5];
  const float* w3 = (const float*)d_in[6];   // [2048,512]
  const float* b3 = (const float*)d_in[7];
  const float* w4 = (const float*)d_in[8];   // [2048,2048]
  const float* b4 = (const float*)d_in[9];
  const float* w5 = (const float*)d_in[10];  // [512,2048]
  const float* b5 = (const float*)d_in[11];
  float* out = (float*)d_out;

  char* ws = (char*)d_ws;
  size_t off = 0;
  auto alloc = [&](size_t bytes) -> void* {
    void* p = ws + off;
    off = (off + bytes + 255) & ~(size_t)255;
    return p;
  };
  __bf16* w1T  = (__bf16*)alloc((size_t)DIN * H1dim * 2);
  __bf16* w4T  = (__bf16*)alloc((size_t)H3dim * H4dim * 2);
  __bf16* w3T  = (__bf16*)alloc((size_t)DOUT * H3dim * 2);
  __bf16* WaT  = (__bf16*)alloc((size_t)DOUT * DIN * 2);
  __bf16* WtT  = (__bf16*)alloc((size_t)DOUT * H3dim * 2);
  __bf16* WcT  = (__bf16*)alloc((size_t)DOUT * DOUT * 2);
  __bf16* q    = (__bf16*)alloc((size_t)Bdim * DOUT * 2);      // 16 MB
  float*  ba   = (float*)alloc(DOUT * 4);
  float*  bc   = (float*)alloc(DOUT * 4);
  float*  part1 = (float*)alloc((size_t)8 * DOUT * DIN * 4);   // 16 MB
  __bf16* xb   = (__bf16*)alloc((size_t)Bdim * DIN * 2);       // 32 MB
  // part2 (4*512*2048*4 = 16 MB) aliases q (16384*512*2 = 16 MB):
  // fold12 writes part2, reduce12 consumes it, q is written only afterwards.
  float*  part2 = (float*)q;

  // 1) three weight transposes + x pre-cast in one dispatch
  prep_kernel<<<9216 + 8192, 256, 0, stream>>>(w1, w1T, w4, w4T, w3, w3T, x, xb);

  // 2) fold1 (WaT partials) + fold2 (WtT partials) in one dispatch
  fold12_kernel<<<2048, 256, 0, stream>>>(w2, w1T, part1, w5, w4T, part2);

  // 3) both reductions in one dispatch
  reduce12_kernel<<<1536, 256, 0, stream>>>(part1, WaT, part2, WtT);

  // 4) fold3 (WcT partials, reuses part1) + folded biases (needs WtT)
  fold3_bias_kernel<<<768, 256, 0, stream>>>(WtT, w3T, part1,
                                             b1, w2, b2, b3, b4, w5, b5, ba, bc);

  // 5) reduce fold3 -> WcT
  reduce_cast_kernel<<<256, 256, 0, stream>>>(part1, WcT, DOUT * DOUT / 4, 8);

  // 6) h2 = xb@Wa + ba -> quantize -> q (all-bf16 DMA)
  gemm_main_kernel<MODE_Q><<<dim3(Bdim / 128, DOUT / 64), 256, 0, stream>>>(
      xb, WaT, q, ba, cb, Bdim, DOUT, DIN);

  // 7) out = q@Wc + bc (all-bf16 DMA)
  gemm_main_kernel<MODE_OUT><<<dim3(Bdim / 128, DOUT / 64), 256, 0, stream>>>(
      q, WcT, out, bc, nullptr, Bdim, DOUT, DOUT);
}

// Round 3
// 290.982 us; speedup vs baseline: 1.2282x; 1.0451x over previous
//
#include <hip/hip_runtime.h>

// ---------------------------------------------------------------------------
// network_49581102465567: 5-layer linear MLP, codebook quantize after layer 2.
// Linear folds: Wa = w2@w1 [512x1024], Wc = (w5@w4)@w3 [512x512].
// Round 8: kill split-K (in-block chunk-grouped accumulation, bit-identical
// left-fold order), 2-phase single-barrier DMA pipeline in all GEMMs,
// dispatch merge 7 -> 4:
//   prep (3 transposes @128B writes + x/w2/w5 casts)
//   foldA (fold1 + fold2 + ba)
//   foldB (fold3 + bc + gemmQ)
//   gemmOUT
// Numerics bit-identical to R7: same RNE casts, same K=32-slice MFMA order,
// same chunk grouping (512/512/256) as the old split-K+reduce left fold.
// ---------------------------------------------------------------------------

typedef __bf16 v8bf __attribute__((ext_vector_type(8)));
typedef float  v4f  __attribute__((ext_vector_type(4)));

#define Bdim   16384
#define DIN    1024
#define DOUT   512
#define H1dim  4096
#define H3dim  2048
#define H4dim  2048

#define GLOBAL_AS __attribute__((address_space(1)))
#define LDS_AS    __attribute__((address_space(3)))

__device__ __forceinline__ void load16_to_lds(const __bf16* g, __bf16* l) {
  __builtin_amdgcn_global_load_lds((const GLOBAL_AS unsigned int*)g,
                                   (LDS_AS unsigned int*)l, 16, 0, 0);
}

__device__ __forceinline__ unsigned pack2bf(float a, float b) {
  return (unsigned)__builtin_bit_cast(unsigned short, (__bf16)a) |
         ((unsigned)__builtin_bit_cast(unsigned short, (__bf16)b) << 16);
}

// ---- prep: transposes (64 in-rows x 32 in-cols -> 128 B writes) + casts ----
__device__ __forceinline__ void transpose_body(const float* __restrict__ in,
                                               __bf16* __restrict__ out,
                                               int R, int C, int bx, int by,
                                               float (*tile)[68]) {
  const int c0 = bx * 32, r0 = by * 64;
  const int t = threadIdx.x, tr = t >> 5, tc = t & 31;
#pragma unroll
  for (int i = 0; i < 8; ++i)
    tile[tc][tr + i * 8] = in[(size_t)(r0 + tr + i * 8) * C + (c0 + tc)];
  __syncthreads();
  const int orow = t >> 3, oc = (t & 7) * 8;      // 32 out-rows x 64 out-cols
  float4 a = *(const float4*)&tile[orow][oc];
  float4 b = *(const float4*)&tile[orow][oc + 4];
  int4 o;
  o.x = pack2bf(a.x, a.y); o.y = pack2bf(a.z, a.w);
  o.z = pack2bf(b.x, b.y); o.w = pack2bf(b.z, b.w);
  *(int4*)&out[(size_t)(c0 + orow) * R + (r0 + oc)] = o;
}

__device__ __forceinline__ void cast_body(const float* __restrict__ in,
                                          __bf16* __restrict__ out, int b) {
  const size_t i = (size_t)b * 2048 + (size_t)threadIdx.x * 8;
  float4 a = *(const float4*)&in[i];
  float4 c = *(const float4*)&in[i + 4];
  int4 o;
  o.x = pack2bf(a.x, a.y); o.y = pack2bf(a.z, a.w);
  o.z = pack2bf(c.x, c.y); o.w = pack2bf(c.z, c.w);
  *(int4*)&out[i] = o;
}

__global__ void prep_kernel(const float* __restrict__ w1, __bf16* __restrict__ w1T,
                            const float* __restrict__ w4, __bf16* __restrict__ w4T,
                            const float* __restrict__ w3, __bf16* __restrict__ w3T,
                            const float* __restrict__ x, __bf16* __restrict__ xb,
                            const float* __restrict__ w2, __bf16* __restrict__ w2b,
                            const float* __restrict__ w5, __bf16* __restrict__ w5b) {
  __shared__ float tile[32][68];
  int b = blockIdx.x;
  if (b < 2048) {                 // w1 [4096][1024] -> w1T [1024][4096]
    transpose_body(w1, w1T, H1dim, DIN, b & 31, b >> 5, tile);
  } else if (b < 4096) {          // w4 [2048][2048] -> w4T [2048][2048]
    b -= 2048;
    transpose_body(w4, w4T, H4dim, H3dim, b & 63, b >> 6, tile);
  } else if (b < 4608) {          // w3 [2048][512] -> w3T [512][2048]
    b -= 4096;
    transpose_body(w3, w3T, H3dim, DOUT, b & 15, b >> 4, tile);
  } else if (b < 12800) {         // x fp32 -> bf16 (16.8M elems)
    cast_body(x, xb, b - 4608);
  } else if (b < 13824) {         // w2 -> bf16 (2M elems)
    cast_body(w2, w2b, b - 12800);
  } else {                        // w5 -> bf16 (1M elems)
    cast_body(w5, w5b, b - 13824);
  }
}

// ---- folded bias bodies (identical math to R7) ----
__device__ __forceinline__ void bias_ba_body(int bb, const float* __restrict__ b1,
                                             const float* __restrict__ w2,
                                             const float* __restrict__ b2,
                                             float* __restrict__ ba) {
  const int wave = threadIdx.x >> 6, lane = threadIdx.x & 63;
  const int j = bb * 4 + wave;
  float s = 0.f;
  for (int k = lane; k < H1dim; k += 64) s += b1[k] * w2[(size_t)j * H1dim + k];
#pragma unroll
  for (int off = 32; off; off >>= 1) s += __shfl_xor(s, off, 64);
  if (lane == 0) ba[j] = s + b2[j];
}

__device__ __forceinline__ void bias_bc_body(int bb, const float* __restrict__ b3,
                                             const __bf16* __restrict__ WtT,
                                             const float* __restrict__ b4,
                                             const float* __restrict__ w5,
                                             const float* __restrict__ b5,
                                             float* __restrict__ bc) {
  const int wave = threadIdx.x >> 6, lane = threadIdx.x & 63;
  const int j = bb * 4 + wave;
  float s = 0.f;
  for (int k = lane; k < H4dim; k += 64)
    s += b3[k] * (float)WtT[(size_t)j * H4dim + k] + b4[k] * w5[(size_t)j * H4dim + k];
#pragma unroll
  for (int off = 32; off; off >>= 1) s += __shfl_xor(s, off, 64);
  if (lane == 0) bc[j] = s + b5[j];
}

// ---- unified bf16 GEMM body: BMx64 tile, BK=64, dbuf 2-phase, swizzled ----
// MODE_W: no bias, chunk-grouped fp32 accumulate (chunk CH k-elems, matching
//         old split-K left-fold), bf16 output.
// MODE_Q: +bias, codebook quantize, bf16 output.
// MODE_OUT: +bias, fp32 output.
enum { MODE_W = 0, MODE_Q = 1, MODE_OUT = 2 };

template <int MODE, int BM>
__device__ __forceinline__ void gemm_body(__bf16* As, __bf16* Bs, float* cbs,
                                          int bx, int by,
                                          const __bf16* __restrict__ A,
                                          const __bf16* __restrict__ Bt,
                                          void* __restrict__ Cout,
                                          const float* __restrict__ bias,
                                          const float* __restrict__ codebook,
                                          int M, int N, int K, int CH) {
  const int t = threadIdx.x;
  const int m0 = bx * BM, n0 = by * 64;
  if constexpr (MODE == MODE_Q) cbs[t] = codebook[t];

  const int lane = t & 63, wave = t >> 6;
  const int quad = lane >> 4, l15 = lane & 15;
  constexpr int MI = BM / 32;                 // A fragments per wave
  const int wm = (wave & 1) * (BM / 2), wn = (wave >> 1) * 32;

  // DMA staging: per gload 64 lanes x 16B = 8 rows x 64 bf16 (linear LDS).
  // Global source chunk is XOR-swizzled by row&7; reads apply the same XOR.
  const int lrow = lane >> 3;
  const int gcol = ((lane & 7) ^ lrow) * 8;
  const __bf16* gA = A  + (size_t)(m0 + (BM / 4) * wave + lrow) * K + gcol;
  const __bf16* gB = Bt + (size_t)(n0 + 16 * wave + lrow) * K + gcol;
  const int swz = l15 & 7;

  v4f acc[MI][2], accT[MI][2];
#pragma unroll
  for (int i = 0; i < MI; ++i)
#pragma unroll
    for (int j = 0; j < 2; ++j) {
      acc[i][j] = (v4f){0.f, 0.f, 0.f, 0.f};
      if constexpr (MODE == MODE_W) accT[i][j] = (v4f){0.f, 0.f, 0.f, 0.f};
    }

  auto stage = [&](int k0, int buf) {
    __bf16* lA = As + buf * (BM * 64) + (BM / 4) * wave * 64;
    __bf16* lB = Bs + buf * (64 * 64) + 16 * wave * 64;
#pragma unroll
    for (int p = 0; p < MI; ++p)
      load16_to_lds(gA + (size_t)(8 * p) * K + k0, lA + p * 512);
#pragma unroll
    for (int p = 0; p < 2; ++p)
      load16_to_lds(gB + (size_t)(8 * p) * K + k0, lB + p * 512);
  };

  stage(0, 0);
  __syncthreads();                 // drains prologue DMA (implicit vmcnt(0))

  const int nk = K >> 6;
  const int chsteps = CH >> 6;
  int cc = 0, buf = 0;
  for (int tk = 0; tk < nk; ++tk) {
    if (tk + 1 < nk) stage((tk + 1) << 6, buf ^ 1);   // prefetch next tile
    const __bf16* cA = As + buf * (BM * 64);
    const __bf16* cB = Bs + buf * (64 * 64);
#pragma unroll
    for (int kk = 0; kk < 2; ++kk) {
      const int cch = ((kk * 4 + quad) ^ swz) * 8;
      v8bf af[MI], bv[2];
#pragma unroll
      for (int i = 0; i < MI; ++i)
        af[i] = *(const v8bf*)&cA[(wm + i * 16 + l15) * 64 + cch];
#pragma unroll
      for (int j = 0; j < 2; ++j)
        bv[j] = *(const v8bf*)&cB[(wn + j * 16 + l15) * 64 + cch];
#pragma unroll
      for (int i = 0; i < MI; ++i)
#pragma unroll
        for (int j = 0; j < 2; ++j)
          acc[i][j] = __builtin_amdgcn_mfma_f32_16x16x32_bf16(af[i], bv[j], acc[i][j], 0, 0, 0);
    }
    if constexpr (MODE == MODE_W) {
      if (++cc == chsteps) {        // chunk boundary: accT += chunk (left fold)
        cc = 0;
#pragma unroll
        for (int i = 0; i < MI; ++i)
#pragma unroll
          for (int j = 0; j < 2; ++j) {
            accT[i][j] += acc[i][j];
            acc[i][j] = (v4f){0.f, 0.f, 0.f, 0.f};
          }
      }
    }
    __syncthreads();               // drains prefetch DMA after compute phase
    buf ^= 1;
  }

#pragma unroll
  for (int j = 0; j < 2; ++j) {
    const int gn = n0 + wn + j * 16 + l15;
    float bj = 0.f;
    if constexpr (MODE != MODE_W) bj = bias[gn];
#pragma unroll
    for (int i = 0; i < MI; ++i) {
#pragma unroll
      for (int r = 0; r < 4; ++r) {
        const int gm = m0 + wm + i * 16 + quad * 4 + r;
        if constexpr (MODE == MODE_W) {
          ((__bf16*)Cout)[(size_t)gm * N + gn] = (__bf16)accT[i][j][r];
        } else if constexpr (MODE == MODE_Q) {
          float v = acc[i][j][r] + bj;
          int idx = 0;
#pragma unroll
          for (int s = 128; s > 0; s >>= 1) {
            const int u = idx + s;
            if (cbs[u] <= v) idx = u;
          }
          float best = cbs[idx];
          if (idx < 255) {
            const float c1 = cbs[idx + 1];
            if (!(v - best <= c1 - v)) best = c1;
          }
          ((__bf16*)Cout)[(size_t)gm * N + gn] = (__bf16)best;
        } else {
          ((float*)Cout)[(size_t)gm * N + gn] = acc[i][j][r] + bj;
        }
      }
    }
  }
}

// ---- dispatch A: fold1 (128 blk) + fold2 (256 blk) + ba (128 blk) ----
__global__ __launch_bounds__(256, 3)
void foldA_kernel(const __bf16* __restrict__ w2b, const __bf16* __restrict__ w1T,
                  __bf16* __restrict__ WaT,
                  const __bf16* __restrict__ w5b, const __bf16* __restrict__ w4T,
                  __bf16* __restrict__ WtT,
                  const float* __restrict__ b1, const float* __restrict__ w2,
                  const float* __restrict__ b2, float* __restrict__ ba) {
  __shared__ __align__(16) __bf16 As[2 * 64 * 64];
  __shared__ __align__(16) __bf16 Bs[2 * 64 * 64];
  int b = blockIdx.x;
  if (b < 128) {        // Wa = w2@w1: M=512, N=1024, K=4096, CH=512
    gemm_body<MODE_W, 64>(As, Bs, nullptr, b & 7, b >> 3, w2b, w1T, WaT,
                          nullptr, nullptr, DOUT, DIN, H1dim, 512);
  } else if (b < 384) { // Wt = w5@w4: M=512, N=2048, K=2048, CH=512
    b -= 128;
    gemm_body<MODE_W, 64>(As, Bs, nullptr, b & 7, b >> 3, w5b, w4T, WtT,
                          nullptr, nullptr, DOUT, H3dim, H4dim, 512);
  } else {              // ba
    bias_ba_body(b - 384, b1, w2, b2, ba);
  }
}

// ---- dispatch B: fold3 (64 blk) + bc (128 blk) + gemmQ (1024 blk) ----
__global__ __launch_bounds__(256, 3)
void foldB_kernel(const __bf16* __restrict__ WtT, const __bf16* __restrict__ w3T,
                  __bf16* __restrict__ WcT,
                  const float* __restrict__ b3, const float* __restrict__ b4,
                  const float* __restrict__ w5, const float* __restrict__ b5,
                  float* __restrict__ bc,
                  const __bf16* __restrict__ xb, const __bf16* __restrict__ WaT,
                  __bf16* __restrict__ q, const float* __restrict__ ba,
                  const float* __restrict__ cb) {
  __shared__ __align__(16) __bf16 As[2 * 128 * 64];
  __shared__ __align__(16) __bf16 Bs[2 * 64 * 64];
  __shared__ float cbs[256];
  int b = blockIdx.x;
  if (b < 64) {         // Wc = Wt@w3: M=512, N=512, K=2048, CH=256
    gemm_body<MODE_W, 64>(As, Bs, nullptr, b & 7, b >> 3, WtT, w3T, WcT,
                          nullptr, nullptr, DOUT, DOUT, H3dim, 256);
  } else if (b < 192) { // bc (needs WtT)
    bias_bc_body(b - 64, b3, WtT, b4, w5, b5, bc);
  } else {              // h2 = xb@Wa + ba -> quantize -> q
    b -= 192;
    gemm_body<MODE_Q, 128>(As, Bs, cbs, b & 127, b >> 7, xb, WaT, q,
                           ba, cb, Bdim, DOUT, DIN, DIN);
  }
}

// ---- dispatch C: out = q@Wc + bc ----
__global__ __launch_bounds__(256, 3)
void gemmout_kernel(const __bf16* __restrict__ q, const __bf16* __restrict__ WcT,
                    float* __restrict__ out, const float* __restrict__ bc) {
  __shared__ __align__(16) __bf16 As[2 * 128 * 64];
  __shared__ __align__(16) __bf16 Bs[2 * 64 * 64];
  gemm_body<MODE_OUT, 128>(As, Bs, nullptr, blockIdx.x & 127, blockIdx.x >> 7,
                           q, WcT, out, bc, nullptr, Bdim, DOUT, DOUT, DOUT);
}

extern "C" void kernel_launch(void* const* d_in, const int* in_sizes, int n_in,
                              void* d_out, int out_size, void* d_ws, size_t ws_size,
                              hipStream_t stream) {
  const float* x  = (const float*)d_in[0];
  const float* cb = (const float*)d_in[1];
  const float* w1 = (const float*)d_in[2];   // [4096,1024]
  const float* b1 = (const float*)d_in[3];
  const float* w2 = (const float*)d_in[4];   // [512,4096]
  const float* b2 = (const float*)d_in[5];
  const float* w3 = (const float*)d_in[6];   // [2048,512]
  const float* b3 = (const float*)d_in[7];
  const float* w4 = (const float*)d_in[8];   // [2048,2048]
  const float* b4 = (const float*)d_in[9];
  const float* w5 = (const float*)d_in[10];  // [512,2048]
  const float* b5 = (const float*)d_in[11];
  float* out = (float*)d_out;

  char* ws = (char*)d_ws;
  size_t off = 0;
  auto alloc = [&](size_t bytes) -> void* {
    void* p = ws + off;
    off = (off + bytes + 255) & ~(size_t)255;
    return p;
  };
  __bf16* w1T = (__bf16*)alloc((size_t)DIN * H1dim * 2);     // 8 MB
  __bf16* w4T = (__bf16*)alloc((size_t)H3dim * H4dim * 2);   // 8 MB
  __bf16* w3T = (__bf16*)alloc((size_t)DOUT * H3dim * 2);    // 2 MB
  __bf16* w2b = (__bf16*)alloc((size_t)DOUT * H1dim * 2);    // 4 MB
  __bf16* w5b = (__bf16*)alloc((size_t)DOUT * H4dim * 2);    // 2 MB
  __bf16* WaT = (__bf16*)alloc((size_t)DOUT * DIN * 2);      // 1 MB
  __bf16* WtT = (__bf16*)alloc((size_t)DOUT * H3dim * 2);    // 2 MB
  __bf16* WcT = (__bf16*)alloc((size_t)DOUT * DOUT * 2);     // 0.5 MB
  __bf16* q   = (__bf16*)alloc((size_t)Bdim * DOUT * 2);     // 16 MB
  __bf16* xb  = (__bf16*)alloc((size_t)Bdim * DIN * 2);      // 32 MB
  float*  ba  = (float*)alloc(DOUT * 4);
  float*  bc  = (float*)alloc(DOUT * 4);

  // 1) transposes (w1,w4,w3) + casts (x,w2,w5)
  prep_kernel<<<14336, 256, 0, stream>>>(w1, w1T, w4, w4T, w3, w3T,
                                         x, xb, w2, w2b, w5, w5b);

  // 2) fold1 + fold2 + ba
  foldA_kernel<<<512, 256, 0, stream>>>(w2b, w1T, WaT, w5b, w4T, WtT,
                                        b1, w2, b2, ba);

  // 3) fold3 + bc + gemmQ
  foldB_kernel<<<1216, 256, 0, stream>>>(WtT, w3T, WcT, b3, b4, w5, b5, bc,
                                         xb, WaT, q, ba, cb);

  // 4) out = q@Wc + bc
  gemmout_kernel<<<1024, 256, 0, stream>>>(q, WcT, out, bc);
}

// Round 5
// 277.791 us; speedup vs baseline: 1.2866x; 1.0475x over previous
//
#include <hip/hip_runtime.h>

// ---------------------------------------------------------------------------
// network_49581102465567: 5-layer linear MLP, codebook quantize after layer 2.
// Linear folds: Wa = w2@w1 [512x1024], Wc = (w5@w4)@w3 [512x512].
// Round 10: R9 counted-vmcnt pipeline + RACE FIX. R9's raw s_barrier let
// waves cross barrier 2 with fragment ds_reads still pending (lgkmcnt!=0);
// the next stage()'s DMA write could land in LDS before the queued ds_read
// was serviced -> sporadic stale reads (absmax 0.023). Fix: explicit
// s_waitcnt lgkmcnt(0) immediately before the second barrier (ds_reads are
// ~64cyc, hidden under MFMA; counted vmcnt pipeline preserved).
// Everything else identical to R8/R9. Numerics bit-identical to R8.
// ---------------------------------------------------------------------------

typedef __bf16 v8bf __attribute__((ext_vector_type(8)));
typedef float  v4f  __attribute__((ext_vector_type(4)));

#define Bdim   16384
#define DIN    1024
#define DOUT   512
#define H1dim  4096
#define H3dim  2048
#define H4dim  2048

#define GLOBAL_AS __attribute__((address_space(1)))
#define LDS_AS    __attribute__((address_space(3)))

__device__ __forceinline__ void load16_to_lds(const __bf16* g, __bf16* l) {
  __builtin_amdgcn_global_load_lds((const GLOBAL_AS unsigned int*)g,
                                   (LDS_AS unsigned int*)l, 16, 0, 0);
}

__device__ __forceinline__ unsigned pack2bf(float a, float b) {
  return (unsigned)__builtin_bit_cast(unsigned short, (__bf16)a) |
         ((unsigned)__builtin_bit_cast(unsigned short, (__bf16)b) << 16);
}

// ---- prep: transposes (64 in-rows x 32 in-cols -> 128 B writes) + casts ----
__device__ __forceinline__ void transpose_body(const float* __restrict__ in,
                                               __bf16* __restrict__ out,
                                               int R, int C, int bx, int by,
                                               float (*tile)[68]) {
  const int c0 = bx * 32, r0 = by * 64;
  const int t = threadIdx.x, tr = t >> 5, tc = t & 31;
#pragma unroll
  for (int i = 0; i < 8; ++i)
    tile[tc][tr + i * 8] = in[(size_t)(r0 + tr + i * 8) * C + (c0 + tc)];
  __syncthreads();
  const int orow = t >> 3, oc = (t & 7) * 8;      // 32 out-rows x 64 out-cols
  float4 a = *(const float4*)&tile[orow][oc];
  float4 b = *(const float4*)&tile[orow][oc + 4];
  int4 o;
  o.x = pack2bf(a.x, a.y); o.y = pack2bf(a.z, a.w);
  o.z = pack2bf(b.x, b.y); o.w = pack2bf(b.z, b.w);
  *(int4*)&out[(size_t)(c0 + orow) * R + (r0 + oc)] = o;
}

__device__ __forceinline__ void cast_body(const float* __restrict__ in,
                                          __bf16* __restrict__ out, int b) {
  const size_t i = (size_t)b * 2048 + (size_t)threadIdx.x * 8;
  float4 a = *(const float4*)&in[i];
  float4 c = *(const float4*)&in[i + 4];
  int4 o;
  o.x = pack2bf(a.x, a.y); o.y = pack2bf(a.z, a.w);
  o.z = pack2bf(c.x, c.y); o.w = pack2bf(c.z, c.w);
  *(int4*)&out[i] = o;
}

__global__ void prep_kernel(const float* __restrict__ w1, __bf16* __restrict__ w1T,
                            const float* __restrict__ w4, __bf16* __restrict__ w4T,
                            const float* __restrict__ w3, __bf16* __restrict__ w3T,
                            const float* __restrict__ x, __bf16* __restrict__ xb,
                            const float* __restrict__ w2, __bf16* __restrict__ w2b,
                            const float* __restrict__ w5, __bf16* __restrict__ w5b) {
  __shared__ float tile[32][68];
  int b = blockIdx.x;
  if (b < 2048) {                 // w1 [4096][1024] -> w1T [1024][4096]
    transpose_body(w1, w1T, H1dim, DIN, b & 31, b >> 5, tile);
  } else if (b < 4096) {          // w4 [2048][2048] -> w4T [2048][2048]
    b -= 2048;
    transpose_body(w4, w4T, H4dim, H3dim, b & 63, b >> 6, tile);
  } else if (b < 4608) {          // w3 [2048][512] -> w3T [512][2048]
    b -= 4096;
    transpose_body(w3, w3T, H3dim, DOUT, b & 15, b >> 4, tile);
  } else if (b < 12800) {         // x fp32 -> bf16 (16.8M elems)
    cast_body(x, xb, b - 4608);
  } else if (b < 13824) {         // w2 -> bf16 (2M elems)
    cast_body(w2, w2b, b - 12800);
  } else {                        // w5 -> bf16 (1M elems)
    cast_body(w5, w5b, b - 13824);
  }
}

// ---- folded bias bodies (identical math to R8) ----
__device__ __forceinline__ void bias_ba_body(int bb, const float* __restrict__ b1,
                                             const float* __restrict__ w2,
                                             const float* __restrict__ b2,
                                             float* __restrict__ ba) {
  const int wave = threadIdx.x >> 6, lane = threadIdx.x & 63;
  const int j = bb * 4 + wave;
  float s = 0.f;
  for (int k = lane; k < H1dim; k += 64) s += b1[k] * w2[(size_t)j * H1dim + k];
#pragma unroll
  for (int off = 32; off; off >>= 1) s += __shfl_xor(s, off, 64);
  if (lane == 0) ba[j] = s + b2[j];
}

__device__ __forceinline__ void bias_bc_body(int bb, const float* __restrict__ b3,
                                             const __bf16* __restrict__ WtT,
                                             const float* __restrict__ b4,
                                             const float* __restrict__ w5,
                                             const float* __restrict__ b5,
                                             float* __restrict__ bc) {
  const int wave = threadIdx.x >> 6, lane = threadIdx.x & 63;
  const int j = bb * 4 + wave;
  float s = 0.f;
  for (int k = lane; k < H4dim; k += 64)
    s += b3[k] * (float)WtT[(size_t)j * H4dim + k] + b4[k] * w5[(size_t)j * H4dim + k];
#pragma unroll
  for (int off = 32; off; off >>= 1) s += __shfl_xor(s, off, 64);
  if (lane == 0) bc[j] = s + b5[j];
}

// ---- unified bf16 GEMM body: BMx64 tile, BK=64, counted-vmcnt pipeline ----
// MODE_W: no bias, chunk-grouped fp32 accumulate (chunk CH k-elems, matching
//         old split-K left-fold), bf16 output.
// MODE_Q: +bias, codebook quantize, bf16 output.
// MODE_OUT: +bias, fp32 output.
enum { MODE_W = 0, MODE_Q = 1, MODE_OUT = 2 };

#define ASM_BAR() asm volatile("s_barrier" ::: "memory")

template <int MODE, int BM>
__device__ __forceinline__ void gemm_body(__bf16* As, __bf16* Bs, float* cbs,
                                          int bx, int by,
                                          const __bf16* __restrict__ A,
                                          const __bf16* __restrict__ Bt,
                                          void* __restrict__ Cout,
                                          const float* __restrict__ bias,
                                          const float* __restrict__ codebook,
                                          int M, int N, int K, int CH) {
  const int t = threadIdx.x;
  const int m0 = bx * BM, n0 = by * 64;
  if constexpr (MODE == MODE_Q) cbs[t] = codebook[t];

  const int lane = t & 63, wave = t >> 6;
  const int quad = lane >> 4, l15 = lane & 15;
  constexpr int MI = BM / 32;                 // A fragments per wave
  const int wm = (wave & 1) * (BM / 2), wn = (wave >> 1) * 32;

  // DMA staging: per gload 64 lanes x 16B = 8 rows x 64 bf16 (linear LDS).
  // Global source chunk is XOR-swizzled by row&7; reads apply the same XOR.
  const int lrow = lane >> 3;
  const int gcol = ((lane & 7) ^ lrow) * 8;
  const __bf16* gA = A  + (size_t)(m0 + (BM / 4) * wave + lrow) * K + gcol;
  const __bf16* gB = Bt + (size_t)(n0 + 16 * wave + lrow) * K + gcol;
  const int swz = l15 & 7;

  v4f acc[MI][2], accT[MI][2];
#pragma unroll
  for (int i = 0; i < MI; ++i)
#pragma unroll
    for (int j = 0; j < 2; ++j) {
      acc[i][j] = (v4f){0.f, 0.f, 0.f, 0.f};
      if constexpr (MODE == MODE_W) accT[i][j] = (v4f){0.f, 0.f, 0.f, 0.f};
    }

  // stage = MI + 2 global_load_lds instructions per wave (LPS)
  auto stage = [&](int k0, int buf) {
    __bf16* lA = As + buf * (BM * 64) + (BM / 4) * wave * 64;
    __bf16* lB = Bs + buf * (64 * 64) + 16 * wave * 64;
#pragma unroll
    for (int p = 0; p < MI; ++p)
      load16_to_lds(gA + (size_t)(8 * p) * K + k0, lA + p * 512);
#pragma unroll
    for (int p = 0; p < 2; ++p)
      load16_to_lds(gB + (size_t)(8 * p) * K + k0, lB + p * 512);
  };

  const int nk = K >> 6;
  const int chsteps = CH >> 6;
  stage(0, 0);
  stage(64, 1);                    // 2*LPS loads in flight

  int cc = 0;
  for (int tk = 0; tk < nk; ++tk) {
    // drain ONLY stage(tk); stage(tk+1)'s LPS loads stay in flight
    if (tk + 1 < nk) {
      if constexpr (BM == 128) asm volatile("s_waitcnt vmcnt(6)" ::: "memory");
      else                     asm volatile("s_waitcnt vmcnt(4)" ::: "memory");
    } else {
      asm volatile("s_waitcnt vmcnt(0)" ::: "memory");
    }
    ASM_BAR();                     // all waves' stage(tk) visible

    const __bf16* cA = As + (tk & 1) * (BM * 64);
    const __bf16* cB = Bs + (tk & 1) * (64 * 64);
#pragma unroll
    for (int kk = 0; kk < 2; ++kk) {
      const int cch = ((kk * 4 + quad) ^ swz) * 8;
      v8bf af[MI], bv[2];
#pragma unroll
      for (int i = 0; i < MI; ++i)
        af[i] = *(const v8bf*)&cA[(wm + i * 16 + l15) * 64 + cch];
#pragma unroll
      for (int j = 0; j < 2; ++j)
        bv[j] = *(const v8bf*)&cB[(wn + j * 16 + l15) * 64 + cch];
#pragma unroll
      for (int i = 0; i < MI; ++i)
#pragma unroll
        for (int j = 0; j < 2; ++j)
          acc[i][j] = __builtin_amdgcn_mfma_f32_16x16x32_bf16(af[i], bv[j], acc[i][j], 0, 0, 0);
    }
    if constexpr (MODE == MODE_W) {
      if (++cc == chsteps) {        // chunk boundary: accT += chunk (left fold)
        cc = 0;
#pragma unroll
        for (int i = 0; i < MI; ++i)
#pragma unroll
          for (int j = 0; j < 2; ++j) {
            accT[i][j] += acc[i][j];
            acc[i][j] = (v4f){0.f, 0.f, 0.f, 0.f};
          }
      }
    }
    // RACE FIX: this wave's fragment ds_reads must complete before any wave
    // may overwrite buf[tk&1] with stage(tk+2) DMA after the barrier.
    asm volatile("s_waitcnt lgkmcnt(0)" ::: "memory");
    ASM_BAR();                     // all waves done reading buf[tk&1]
    if (tk + 2 < nk) stage((tk + 2) << 6, tk & 1);   // refill freed buffer
  }

#pragma unroll
  for (int j = 0; j < 2; ++j) {
    const int gn = n0 + wn + j * 16 + l15;
    float bj = 0.f;
    if constexpr (MODE != MODE_W) bj = bias[gn];
#pragma unroll
    for (int i = 0; i < MI; ++i) {
#pragma unroll
      for (int r = 0; r < 4; ++r) {
        const int gm = m0 + wm + i * 16 + quad * 4 + r;
        if constexpr (MODE == MODE_W) {
          ((__bf16*)Cout)[(size_t)gm * N + gn] = (__bf16)accT[i][j][r];
        } else if constexpr (MODE == MODE_Q) {
          float v = acc[i][j][r] + bj;
          int idx = 0;
#pragma unroll
          for (int s = 128; s > 0; s >>= 1) {
            const int u = idx + s;
            if (cbs[u] <= v) idx = u;
          }
          float best = cbs[idx];
          if (idx < 255) {
            const float c1 = cbs[idx + 1];
            if (!(v - best <= c1 - v)) best = c1;
          }
          ((__bf16*)Cout)[(size_t)gm * N + gn] = (__bf16)best;
        } else {
          ((float*)Cout)[(size_t)gm * N + gn] = acc[i][j][r] + bj;
        }
      }
    }
  }
}

// ---- dispatch A: fold1 (128 blk) + fold2 (256 blk) + ba (128 blk) ----
__global__ __launch_bounds__(256, 3)
void foldA_kernel(const __bf16* __restrict__ w2b, const __bf16* __restrict__ w1T,
                  __bf16* __restrict__ WaT,
                  const __bf16* __restrict__ w5b, const __bf16* __restrict__ w4T,
                  __bf16* __restrict__ WtT,
                  const float* __restrict__ b1, const float* __restrict__ w2,
                  const float* __restrict__ b2, float* __restrict__ ba) {
  __shared__ __align__(16) __bf16 As[2 * 64 * 64];
  __shared__ __align__(16) __bf16 Bs[2 * 64 * 64];
  int b = blockIdx.x;
  if (b < 128) {        // Wa = w2@w1: M=512, N=1024, K=4096, CH=512
    gemm_body<MODE_W, 64>(As, Bs, nullptr, b & 7, b >> 3, w2b, w1T, WaT,
                          nullptr, nullptr, DOUT, DIN, H1dim, 512);
  } else if (b < 384) { // Wt = w5@w4: M=512, N=2048, K=2048, CH=512
    b -= 128;
    gemm_body<MODE_W, 64>(As, Bs, nullptr, b & 7, b >> 3, w5b, w4T, WtT,
                          nullptr, nullptr, DOUT, H3dim, H4dim, 512);
  } else {              // ba
    bias_ba_body(b - 384, b1, w2, b2, ba);
  }
}

// ---- dispatch B: fold3 (64 blk) + bc (128 blk) + gemmQ (1024 blk) ----
__global__ __launch_bounds__(256, 3)
void foldB_kernel(const __bf16* __restrict__ WtT, const __bf16* __restrict__ w3T,
                  __bf16* __restrict__ WcT,
                  const float* __restrict__ b3, const float* __restrict__ b4,
                  const float* __restrict__ w5, const float* __restrict__ b5,
                  float* __restrict__ bc,
                  const __bf16* __restrict__ xb, const __bf16* __restrict__ WaT,
                  __bf16* __restrict__ q, const float* __restrict__ ba,
                  const float* __restrict__ cb) {
  __shared__ __align__(16) __bf16 As[2 * 128 * 64];
  __shared__ __align__(16) __bf16 Bs[2 * 64 * 64];
  __shared__ float cbs[256];
  int b = blockIdx.x;
  if (b < 64) {         // Wc = Wt@w3: M=512, N=512, K=2048, CH=256
    gemm_body<MODE_W, 64>(As, Bs, nullptr, b & 7, b >> 3, WtT, w3T, WcT,
                          nullptr, nullptr, DOUT, DOUT, H3dim, 256);
  } else if (b < 192) { // bc (needs WtT)
    bias_bc_body(b - 64, b3, WtT, b4, w5, b5, bc);
  } else {              // h2 = xb@Wa + ba -> quantize -> q
    b -= 192;
    gemm_body<MODE_Q, 128>(As, Bs, cbs, b & 127, b >> 7, xb, WaT, q,
                           ba, cb, Bdim, DOUT, DIN, DIN);
  }
}

// ---- dispatch C: out = q@Wc + bc ----
__global__ __launch_bounds__(256, 3)
void gemmout_kernel(const __bf16* __restrict__ q, const __bf16* __restrict__ WcT,
                    float* __restrict__ out, const float* __restrict__ bc) {
  __shared__ __align__(16) __bf16 As[2 * 128 * 64];
  __shared__ __align__(16) __bf16 Bs[2 * 64 * 64];
  gemm_body<MODE_OUT, 128>(As, Bs, nullptr, blockIdx.x & 127, blockIdx.x >> 7,
                           q, WcT, out, bc, nullptr, Bdim, DOUT, DOUT, DOUT);
}

extern "C" void kernel_launch(void* const* d_in, const int* in_sizes, int n_in,
                              void* d_out, int out_size, void* d_ws, size_t ws_size,
                              hipStream_t stream) {
  const float* x  = (const float*)d_in[0];
  const float* cb = (const float*)d_in[1];
  const float* w1 = (const float*)d_in[2];   // [4096,1024]
  const float* b1 = (const float*)d_in[3];
  const float* w2 = (const float*)d_in[4];   // [512,4096]
  const float* b2 = (const float*)d_in[5];
  const float* w3 = (const float*)d_in[6];   // [2048,512]
  const float* b3 = (const float*)d_in[7];
  const float* w4 = (const float*)d_in[8];   // [2048,2048]
  const float* b4 = (const float*)d_in[9];
  const float* w5 = (const float*)d_in[10];  // [512,2048]
  const float* b5 = (const float*)d_in[11];
  float* out = (float*)d_out;

  char* ws = (char*)d_ws;
  size_t off = 0;
  auto alloc = [&](size_t bytes) -> void* {
    void* p = ws + off;
    off = (off + bytes + 255) & ~(size_t)255;
    return p;
  };
  __bf16* w1T = (__bf16*)alloc((size_t)DIN * H1dim * 2);     // 8 MB
  __bf16* w4T = (__bf16*)alloc((size_t)H3dim * H4dim * 2);   // 8 MB
  __bf16* w3T = (__bf16*)alloc((size_t)DOUT * H3dim * 2);    // 2 MB
  __bf16* w2b = (__bf16*)alloc((size_t)DOUT * H1dim * 2);    // 4 MB
  __bf16* w5b = (__bf16*)alloc((size_t)DOUT * H4dim * 2);    // 2 MB
  __bf16* WaT = (__bf16*)alloc((size_t)DOUT * DIN * 2);      // 1 MB
  __bf16* WtT = (__bf16*)alloc((size_t)DOUT * H3dim * 2);    // 2 MB
  __bf16* WcT = (__bf16*)alloc((size_t)DOUT * DOUT * 2);     // 0.5 MB
  __bf16* q   = (__bf16*)alloc((size_t)Bdim * DOUT * 2);     // 16 MB
  __bf16* xb  = (__bf16*)alloc((size_t)Bdim * DIN * 2);      // 32 MB
  float*  ba  = (float*)alloc(DOUT * 4);
  float*  bc  = (float*)alloc(DOUT * 4);

  // 1) transposes (w1,w4,w3) + casts (x,w2,w5)
  prep_kernel<<<14336, 256, 0, stream>>>(w1, w1T, w4, w4T, w3, w3T,
                                         x, xb, w2, w2b, w5, w5b);

  // 2) fold1 + fold2 + ba
  foldA_kernel<<<512, 256, 0, stream>>>(w2b, w1T, WaT, w5b, w4T, WtT,
                                        b1, w2, b2, ba);

  // 3) fold3 + bc + gemmQ
  foldB_kernel<<<1216, 256, 0, stream>>>(WtT, w3T, WcT, b3, b4, w5, b5, bc,
                                         xb, WaT, q, ba, cb);

  // 4) out = q@Wc + bc
  gemmout_kernel<<<1024, 256, 0, stream>>>(q, WcT, out, bc);
}

// Round 6
// 267.965 us; speedup vs baseline: 1.3337x; 1.0367x over previous
//
#include <hip/hip_runtime.h>

// ---------------------------------------------------------------------------
// network_49581102465567: 5-layer linear MLP, codebook quantize after layer 2.
// Linear folds: Wa = w2@w1 [512x1024], Wc = (w5@w4)@w3 [512x512].
// Round 11: XCD-locality block remap. R10 counters: gemmQ's MFMA-busy time
// == ideal (6.8us) but 88% stall; cause is 384 MB of L2-miss traffic from
// xb re-read 8x across column tiles (LLC-bound at ~6.7 TB/s). Remap block
// indices so blocks sharing an A-panel run consecutively on ONE XCD
// (XCD = blockIdx%8): panel fetched from LLC once, B matrix L2-resident.
//   gemmQ/gemmout: c=b%8,i=b/8 -> bx=c*16+i/8, by=i&7   (A-panel locality)
//   fold1: by=c*2+(i&1), bx=i>>1; fold2: by=c*4+(i&3), bx=i>>2; fold3: by=c
//     (N-partition: B streams once per XCD, small A L2-resident)
// Bijective relabeling only — per-block work, sync, numerics identical to
// R10 (passed, absmax 0.0059).
// ---------------------------------------------------------------------------

typedef __bf16 v8bf __attribute__((ext_vector_type(8)));
typedef float  v4f  __attribute__((ext_vector_type(4)));

#define Bdim   16384
#define DIN    1024
#define DOUT   512
#define H1dim  4096
#define H3dim  2048
#define H4dim  2048

#define GLOBAL_AS __attribute__((address_space(1)))
#define LDS_AS    __attribute__((address_space(3)))

__device__ __forceinline__ void load16_to_lds(const __bf16* g, __bf16* l) {
  __builtin_amdgcn_global_load_lds((const GLOBAL_AS unsigned int*)g,
                                   (LDS_AS unsigned int*)l, 16, 0, 0);
}

__device__ __forceinline__ unsigned pack2bf(float a, float b) {
  return (unsigned)__builtin_bit_cast(unsigned short, (__bf16)a) |
         ((unsigned)__builtin_bit_cast(unsigned short, (__bf16)b) << 16);
}

// ---- prep: transposes (64 in-rows x 32 in-cols -> 128 B writes) + casts ----
__device__ __forceinline__ void transpose_body(const float* __restrict__ in,
                                               __bf16* __restrict__ out,
                                               int R, int C, int bx, int by,
                                               float (*tile)[68]) {
  const int c0 = bx * 32, r0 = by * 64;
  const int t = threadIdx.x, tr = t >> 5, tc = t & 31;
#pragma unroll
  for (int i = 0; i < 8; ++i)
    tile[tc][tr + i * 8] = in[(size_t)(r0 + tr + i * 8) * C + (c0 + tc)];
  __syncthreads();
  const int orow = t >> 3, oc = (t & 7) * 8;      // 32 out-rows x 64 out-cols
  float4 a = *(const float4*)&tile[orow][oc];
  float4 b = *(const float4*)&tile[orow][oc + 4];
  int4 o;
  o.x = pack2bf(a.x, a.y); o.y = pack2bf(a.z, a.w);
  o.z = pack2bf(b.x, b.y); o.w = pack2bf(b.z, b.w);
  *(int4*)&out[(size_t)(c0 + orow) * R + (r0 + oc)] = o;
}

__device__ __forceinline__ void cast_body(const float* __restrict__ in,
                                          __bf16* __restrict__ out, int b) {
  const size_t i = (size_t)b * 2048 + (size_t)threadIdx.x * 8;
  float4 a = *(const float4*)&in[i];
  float4 c = *(const float4*)&in[i + 4];
  int4 o;
  o.x = pack2bf(a.x, a.y); o.y = pack2bf(a.z, a.w);
  o.z = pack2bf(c.x, c.y); o.w = pack2bf(c.z, c.w);
  *(int4*)&out[i] = o;
}

__global__ void prep_kernel(const float* __restrict__ w1, __bf16* __restrict__ w1T,
                            const float* __restrict__ w4, __bf16* __restrict__ w4T,
                            const float* __restrict__ w3, __bf16* __restrict__ w3T,
                            const float* __restrict__ x, __bf16* __restrict__ xb,
                            const float* __restrict__ w2, __bf16* __restrict__ w2b,
                            const float* __restrict__ w5, __bf16* __restrict__ w5b) {
  __shared__ float tile[32][68];
  int b = blockIdx.x;
  if (b < 2048) {                 // w1 [4096][1024] -> w1T [1024][4096]
    transpose_body(w1, w1T, H1dim, DIN, b & 31, b >> 5, tile);
  } else if (b < 4096) {          // w4 [2048][2048] -> w4T [2048][2048]
    b -= 2048;
    transpose_body(w4, w4T, H4dim, H3dim, b & 63, b >> 6, tile);
  } else if (b < 4608) {          // w3 [2048][512] -> w3T [512][2048]
    b -= 4096;
    transpose_body(w3, w3T, H3dim, DOUT, b & 15, b >> 4, tile);
  } else if (b < 12800) {         // x fp32 -> bf16 (16.8M elems)
    cast_body(x, xb, b - 4608);
  } else if (b < 13824) {         // w2 -> bf16 (2M elems)
    cast_body(w2, w2b, b - 12800);
  } else {                        // w5 -> bf16 (1M elems)
    cast_body(w5, w5b, b - 13824);
  }
}

// ---- folded bias bodies (identical math to R10) ----
__device__ __forceinline__ void bias_ba_body(int bb, const float* __restrict__ b1,
                                             const float* __restrict__ w2,
                                             const float* __restrict__ b2,
                                             float* __restrict__ ba) {
  const int wave = threadIdx.x >> 6, lane = threadIdx.x & 63;
  const int j = bb * 4 + wave;
  float s = 0.f;
  for (int k = lane; k < H1dim; k += 64) s += b1[k] * w2[(size_t)j * H1dim + k];
#pragma unroll
  for (int off = 32; off; off >>= 1) s += __shfl_xor(s, off, 64);
  if (lane == 0) ba[j] = s + b2[j];
}

__device__ __forceinline__ void bias_bc_body(int bb, const float* __restrict__ b3,
                                             const __bf16* __restrict__ WtT,
                                             const float* __restrict__ b4,
                                             const float* __restrict__ w5,
                                             const float* __restrict__ b5,
                                             float* __restrict__ bc) {
  const int wave = threadIdx.x >> 6, lane = threadIdx.x & 63;
  const int j = bb * 4 + wave;
  float s = 0.f;
  for (int k = lane; k < H4dim; k += 64)
    s += b3[k] * (float)WtT[(size_t)j * H4dim + k] + b4[k] * w5[(size_t)j * H4dim + k];
#pragma unroll
  for (int off = 32; off; off >>= 1) s += __shfl_xor(s, off, 64);
  if (lane == 0) bc[j] = s + b5[j];
}

// ---- unified bf16 GEMM body: BMx64 tile, BK=64, counted-vmcnt pipeline ----
enum { MODE_W = 0, MODE_Q = 1, MODE_OUT = 2 };

#define ASM_BAR() asm volatile("s_barrier" ::: "memory")

template <int MODE, int BM>
__device__ __forceinline__ void gemm_body(__bf16* As, __bf16* Bs, float* cbs,
                                          int bx, int by,
                                          const __bf16* __restrict__ A,
                                          const __bf16* __restrict__ Bt,
                                          void* __restrict__ Cout,
                                          const float* __restrict__ bias,
                                          const float* __restrict__ codebook,
                                          int M, int N, int K, int CH) {
  const int t = threadIdx.x;
  const int m0 = bx * BM, n0 = by * 64;
  if constexpr (MODE == MODE_Q) cbs[t] = codebook[t];

  const int lane = t & 63, wave = t >> 6;
  const int quad = lane >> 4, l15 = lane & 15;
  constexpr int MI = BM / 32;                 // A fragments per wave
  const int wm = (wave & 1) * (BM / 2), wn = (wave >> 1) * 32;

  // DMA staging: per gload 64 lanes x 16B = 8 rows x 64 bf16 (linear LDS).
  // Global source chunk is XOR-swizzled by row&7; reads apply the same XOR.
  const int lrow = lane >> 3;
  const int gcol = ((lane & 7) ^ lrow) * 8;
  const __bf16* gA = A  + (size_t)(m0 + (BM / 4) * wave + lrow) * K + gcol;
  const __bf16* gB = Bt + (size_t)(n0 + 16 * wave + lrow) * K + gcol;
  const int swz = l15 & 7;

  v4f acc[MI][2], accT[MI][2];
#pragma unroll
  for (int i = 0; i < MI; ++i)
#pragma unroll
    for (int j = 0; j < 2; ++j) {
      acc[i][j] = (v4f){0.f, 0.f, 0.f, 0.f};
      if constexpr (MODE == MODE_W) accT[i][j] = (v4f){0.f, 0.f, 0.f, 0.f};
    }

  // stage = MI + 2 global_load_lds instructions per wave (LPS)
  auto stage = [&](int k0, int buf) {
    __bf16* lA = As + buf * (BM * 64) + (BM / 4) * wave * 64;
    __bf16* lB = Bs + buf * (64 * 64) + 16 * wave * 64;
#pragma unroll
    for (int p = 0; p < MI; ++p)
      load16_to_lds(gA + (size_t)(8 * p) * K + k0, lA + p * 512);
#pragma unroll
    for (int p = 0; p < 2; ++p)
      load16_to_lds(gB + (size_t)(8 * p) * K + k0, lB + p * 512);
  };

  const int nk = K >> 6;
  const int chsteps = CH >> 6;
  stage(0, 0);
  stage(64, 1);                    // 2*LPS loads in flight

  int cc = 0;
  for (int tk = 0; tk < nk; ++tk) {
    // drain ONLY stage(tk); stage(tk+1)'s LPS loads stay in flight
    if (tk + 1 < nk) {
      if constexpr (BM == 128) asm volatile("s_waitcnt vmcnt(6)" ::: "memory");
      else                     asm volatile("s_waitcnt vmcnt(4)" ::: "memory");
    } else {
      asm volatile("s_waitcnt vmcnt(0)" ::: "memory");
    }
    ASM_BAR();                     // all waves' stage(tk) visible

    const __bf16* cA = As + (tk & 1) * (BM * 64);
    const __bf16* cB = Bs + (tk & 1) * (64 * 64);
#pragma unroll
    for (int kk = 0; kk < 2; ++kk) {
      const int cch = ((kk * 4 + quad) ^ swz) * 8;
      v8bf af[MI], bv[2];
#pragma unroll
      for (int i = 0; i < MI; ++i)
        af[i] = *(const v8bf*)&cA[(wm + i * 16 + l15) * 64 + cch];
#pragma unroll
      for (int j = 0; j < 2; ++j)
        bv[j] = *(const v8bf*)&cB[(wn + j * 16 + l15) * 64 + cch];
#pragma unroll
      for (int i = 0; i < MI; ++i)
#pragma unroll
        for (int j = 0; j < 2; ++j)
          acc[i][j] = __builtin_amdgcn_mfma_f32_16x16x32_bf16(af[i], bv[j], acc[i][j], 0, 0, 0);
    }
    if constexpr (MODE == MODE_W) {
      if (++cc == chsteps) {        // chunk boundary: accT += chunk (left fold)
        cc = 0;
#pragma unroll
        for (int i = 0; i < MI; ++i)
#pragma unroll
          for (int j = 0; j < 2; ++j) {
            accT[i][j] += acc[i][j];
            acc[i][j] = (v4f){0.f, 0.f, 0.f, 0.f};
          }
      }
    }
    // Race fix (R10): fragment ds_reads must complete before any wave may
    // overwrite buf[tk&1] with stage(tk+2) DMA after the barrier.
    asm volatile("s_waitcnt lgkmcnt(0)" ::: "memory");
    ASM_BAR();                     // all waves done reading buf[tk&1]
    if (tk + 2 < nk) stage((tk + 2) << 6, tk & 1);   // refill freed buffer
  }

#pragma unroll
  for (int j = 0; j < 2; ++j) {
    const int gn = n0 + wn + j * 16 + l15;
    float bj = 0.f;
    if constexpr (MODE != MODE_W) bj = bias[gn];
#pragma unroll
    for (int i = 0; i < MI; ++i) {
#pragma unroll
      for (int r = 0; r < 4; ++r) {
        const int gm = m0 + wm + i * 16 + quad * 4 + r;
        if constexpr (MODE == MODE_W) {
          ((__bf16*)Cout)[(size_t)gm * N + gn] = (__bf16)accT[i][j][r];
        } else if constexpr (MODE == MODE_Q) {
          float v = acc[i][j][r] + bj;
          int idx = 0;
#pragma unroll
          for (int s = 128; s > 0; s >>= 1) {
            const int u = idx + s;
            if (cbs[u] <= v) idx = u;
          }
          float best = cbs[idx];
          if (idx < 255) {
            const float c1 = cbs[idx + 1];
            if (!(v - best <= c1 - v)) best = c1;
          }
          ((__bf16*)Cout)[(size_t)gm * N + gn] = (__bf16)best;
        } else {
          ((float*)Cout)[(size_t)gm * N + gn] = acc[i][j][r] + bj;
        }
      }
    }
  }
}

// ---- dispatch A: fold1 (128 blk) + fold2 (256 blk) + ba (128 blk) ----
// XCD remap: partition by N (B streams once per XCD; small A L2-resident).
__global__ __launch_bounds__(256, 3)
void foldA_kernel(const __bf16* __restrict__ w2b, const __bf16* __restrict__ w1T,
                  __bf16* __restrict__ WaT,
                  const __bf16* __restrict__ w5b, const __bf16* __restrict__ w4T,
                  __bf16* __restrict__ WtT,
                  const float* __restrict__ b1, const float* __restrict__ w2,
                  const float* __restrict__ b2, float* __restrict__ ba) {
  __shared__ __align__(16) __bf16 As[2 * 64 * 64];
  __shared__ __align__(16) __bf16 Bs[2 * 64 * 64];
  int b = blockIdx.x;
  if (b < 128) {        // Wa = w2@w1: M=512, N=1024, K=4096, CH=512
    const int c = b & 7, i = b >> 3;            // XCD c gets by {2c,2c+1}
    gemm_body<MODE_W, 64>(As, Bs, nullptr, i >> 1, c * 2 + (i & 1), w2b, w1T, WaT,
                          nullptr, nullptr, DOUT, DIN, H1dim, 512);
  } else if (b < 384) { // Wt = w5@w4: M=512, N=2048, K=2048, CH=512
    b -= 128;
    const int c = b & 7, i = b >> 3;            // XCD c gets by {4c..4c+3}
    gemm_body<MODE_W, 64>(As, Bs, nullptr, i >> 2, c * 4 + (i & 3), w5b, w4T, WtT,
                          nullptr, nullptr, DOUT, H3dim, H4dim, 512);
  } else {              // ba
    bias_ba_body(b - 384, b1, w2, b2, ba);
  }
}

// ---- dispatch B: fold3 (64 blk) + bc (128 blk) + gemmQ (1024 blk) ----
__global__ __launch_bounds__(256, 3)
void foldB_kernel(const __bf16* __restrict__ WtT, const __bf16* __restrict__ w3T,
                  __bf16* __restrict__ WcT,
                  const float* __restrict__ b3, const float* __restrict__ b4,
                  const float* __restrict__ w5, const float* __restrict__ b5,
                  float* __restrict__ bc,
                  const __bf16* __restrict__ xb, const __bf16* __restrict__ WaT,
                  __bf16* __restrict__ q, const float* __restrict__ ba,
                  const float* __restrict__ cb) {
  __shared__ __align__(16) __bf16 As[2 * 128 * 64];
  __shared__ __align__(16) __bf16 Bs[2 * 64 * 64];
  __shared__ float cbs[256];
  int b = blockIdx.x;
  if (b < 64) {         // Wc = Wt@w3: M=512, N=512, K=2048, CH=256
    const int c = b & 7, i = b >> 3;            // XCD c gets by=c
    gemm_body<MODE_W, 64>(As, Bs, nullptr, i, c, WtT, w3T, WcT,
                          nullptr, nullptr, DOUT, DOUT, H3dim, 256);
  } else if (b < 192) { // bc (needs WtT)
    bias_bc_body(b - 64, b3, WtT, b4, w5, b5, bc);
  } else {              // h2 = xb@Wa + ba -> quantize -> q
    b -= 192;           // 192 % 8 == 0 -> XCD = b % 8 preserved
    // XCD c: bx in [16c,16c+16); 8 consecutive blocks share one xb panel
    const int c = b & 7, i = b >> 3;
    gemm_body<MODE_Q, 128>(As, Bs, cbs, c * 16 + (i >> 3), i & 7, xb, WaT, q,
                           ba, cb, Bdim, DOUT, DIN, DIN);
  }
}

// ---- dispatch C: out = q@Wc + bc ----
__global__ __launch_bounds__(256, 3)
void gemmout_kernel(const __bf16* __restrict__ q, const __bf16* __restrict__ WcT,
                    float* __restrict__ out, const float* __restrict__ bc) {
  __shared__ __align__(16) __bf16 As[2 * 128 * 64];
  __shared__ __align__(16) __bf16 Bs[2 * 64 * 64];
  const int b = blockIdx.x;
  const int c = b & 7, i = b >> 3;              // same remap as gemmQ
  gemm_body<MODE_OUT, 128>(As, Bs, nullptr, c * 16 + (i >> 3), i & 7,
                           q, WcT, out, bc, nullptr, Bdim, DOUT, DOUT, DOUT);
}

extern "C" void kernel_launch(void* const* d_in, const int* in_sizes, int n_in,
                              void* d_out, int out_size, void* d_ws, size_t ws_size,
                              hipStream_t stream) {
  const float* x  = (const float*)d_in[0];
  const float* cb = (const float*)d_in[1];
  const float* w1 = (const float*)d_in[2];   // [4096,1024]
  const float* b1 = (const float*)d_in[3];
  const float* w2 = (const float*)d_in[4];   // [512,4096]
  const float* b2 = (const float*)d_in[5];
  const float* w3 = (const float*)d_in[6];   // [2048,512]
  const float* b3 = (const float*)d_in[7];
  const float* w4 = (const float*)d_in[8];   // [2048,2048]
  const float* b4 = (const float*)d_in[9];
  const float* w5 = (const float*)d_in[10];  // [512,2048]
  const float* b5 = (const float*)d_in[11];
  float* out = (float*)d_out;

  char* ws = (char*)d_ws;
  size_t off = 0;
  auto alloc = [&](size_t bytes) -> void* {
    void* p = ws + off;
    off = (off + bytes + 255) & ~(size_t)255;
    return p;
  };
  __bf16* w1T = (__bf16*)alloc((size_t)DIN * H1dim * 2);     // 8 MB
  __bf16* w4T = (__bf16*)alloc((size_t)H3dim * H4dim * 2);   // 8 MB
  __bf16* w3T = (__bf16*)alloc((size_t)DOUT * H3dim * 2);    // 2 MB
  __bf16* w2b = (__bf16*)alloc((size_t)DOUT * H1dim * 2);    // 4 MB
  __bf16* w5b = (__bf16*)alloc((size_t)DOUT * H4dim * 2);    // 2 MB
  __bf16* WaT = (__bf16*)alloc((size_t)DOUT * DIN * 2);      // 1 MB
  __bf16* WtT = (__bf16*)alloc((size_t)DOUT * H3dim * 2);    // 2 MB
  __bf16* WcT = (__bf16*)alloc((size_t)DOUT * DOUT * 2);     // 0.5 MB
  __bf16* q   = (__bf16*)alloc((size_t)Bdim * DOUT * 2);     // 16 MB
  __bf16* xb  = (__bf16*)alloc((size_t)Bdim * DIN * 2);      // 32 MB
  float*  ba  = (float*)alloc(DOUT * 4);
  float*  bc  = (float*)alloc(DOUT * 4);

  // 1) transposes (w1,w4,w3) + casts (x,w2,w5)
  prep_kernel<<<14336, 256, 0, stream>>>(w1, w1T, w4, w4T, w3, w3T,
                                         x, xb, w2, w2b, w5, w5b);

  // 2) fold1 + fold2 + ba
  foldA_kernel<<<512, 256, 0, stream>>>(w2b, w1T, WaT, w5b, w4T, WtT,
                                        b1, w2, b2, ba);

  // 3) fold3 + bc + gemmQ
  foldB_kernel<<<1216, 256, 0, stream>>>(WtT, w3T, WcT, b3, b4, w5, b5, bc,
                                         xb, WaT, q, ba, cb);

  // 4) out = q@Wc + bc
  gemmout_kernel<<<1024, 256, 0, stream>>>(q, WcT, out, bc);
}